// Round 15
// baseline (188.961 us; speedup 1.0000x reference)
//
#include <hip/hip_runtime.h>
#include <stdint.h>

typedef __attribute__((ext_vector_type(8))) short short8;   // 8 bf16 (4 VGPRs)
typedef __attribute__((ext_vector_type(4))) float f32x4;

#define LDS_AS __attribute__((address_space(3)))
#define GLOB_AS __attribute__((address_space(1)))

__device__ __forceinline__ void gload_lds16(const void* g, void* l) {
    __builtin_amdgcn_global_load_lds((const GLOB_AS uint32_t*)g,
                                     (LDS_AS uint32_t*)l, 16, 0, 0);
}

__device__ __forceinline__ unsigned short f2bf(float f) {
    uint32_t u = __builtin_bit_cast(uint32_t, f);
    u += 0x7fffu + ((u >> 16) & 1u);
    return (unsigned short)(u >> 16);
}
__device__ __forceinline__ float bf2f(unsigned short u) {
    uint32_t v = ((uint32_t)u) << 16;
    return __builtin_bit_cast(float, v);
}

// ------------- fused fp32 -> bf16 convert (x, qkv_w, proj_w) -------------
__global__ void cvt3_kernel(const float* __restrict__ s0,
                            const float* __restrict__ s1,
                            const float* __restrict__ s2,
                            unsigned short* __restrict__ d0,
                            unsigned short* __restrict__ d1,
                            unsigned short* __restrict__ d2) {
    long e = ((long)blockIdx.x * blockDim.x + threadIdx.x) * 4;
    const float* s; unsigned short* d; long off;
    if (e < 8388608)        { s = s0; d = d0; off = e; }
    else if (e < 11534336)  { s = s1; d = d1; off = e - 8388608; }
    else                    { s = s2; d = d2; off = e - 11534336; }
    float4 v = *(const float4*)(s + off);
    ushort4 o;
    o.x = f2bf(v.x); o.y = f2bf(v.y); o.z = f2bf(v.z); o.w = f2bf(v.w);
    *(ushort4*)(d + off) = o;
}

// ---------------- rope tables: cos/sin (2048 x 32) ----------------
__global__ void rope_tables(float* __restrict__ cosT, float* __restrict__ sinT) {
    int tid = blockIdx.x * blockDim.x + threadIdx.x;  // 65536
    int t = tid >> 5, i = tid & 31;
    float f = (i < 16) ? exp2f(-10.0f * (float)i / 15.0f) : 0.0f;
    float th = (float)t * f;
    cosT[tid] = cosf(th);
    sinT[tid] = sinf(th);
}

// ==== GEMM (round-8 champion + packed vbT stores) ========================
// BM=256 BN=128, 8 waves (4M x 2N, 64x64/wave), 3-K-tile LDS ring,
// counted vmcnt(6), XCD-L2 tile mapping. vbT epilogue: 4 consecutive-t bf16
// packed into one ushort4 (8-B) store instead of four 2-B scatters.
// MODE 1: qkv epilogue (q/k RMS+RoPE; v lerp -> vout + vbT). MODE 2: +bias.
template <int MODE>
__global__ __launch_bounds__(512, 2) void gemm8p(
    const unsigned short* __restrict__ A, const unsigned short* __restrict__ B,
    int K,
    unsigned short* __restrict__ qbuf, unsigned short* __restrict__ kbuf,
    float* __restrict__ vout, unsigned short* __restrict__ vbT,
    const float* __restrict__ v1, const float* __restrict__ lambp,
    float* __restrict__ y, const float* __restrict__ bias,
    const float* __restrict__ cosT, const float* __restrict__ sinT)
{
    __shared__ __align__(16) char smem[147456];   // A ring 98304 + B ring 49152
    char* const AL = smem;
    char* const BL = smem + 98304;
    const int tid = threadIdx.x, lane = tid & 63, w = tid >> 6;
    const int wr = w >> 1, wc = w & 1;
    const int lr = lane & 15, lh = lane >> 4;

    // XCD-L2 tile mapping (XCD = id%8 round-robin assumption)
    const int id = blockIdx.x;
    const long m0 = (long)((id & 7) * 4 + ((id >> 3) & 3)) * 256;
    const long n0 = (long)(id >> 5) * 128;
    const int NT = K >> 6;

    const int srow = tid >> 3;
    const int swc  = (tid & 7) ^ (srow & 7);
    const long rsb = (long)K * 2;
    const char* pa0 = (const char*)A + (m0 + srow +   0) * rsb + swc * 16;
    const char* pa1 = (const char*)A + (m0 + srow +  64) * rsb + swc * 16;
    const char* pa2 = (const char*)A + (m0 + srow + 128) * rsb + swc * 16;
    const char* pa3 = (const char*)A + (m0 + srow + 192) * rsb + swc * 16;
    const char* pb0 = (const char*)B + (n0 + srow +   0) * rsb + swc * 16;
    const char* pb1 = (const char*)B + (n0 + srow +  64) * rsb + swc * 16;
    char* const lA = AL + w * 1024;
    char* const lB = BL + w * 1024;

    auto STAGE_A3 = [&](int aoff, int boff) {
        gload_lds16(pa0, lA + aoff);
        gload_lds16(pa1, lA + aoff + 8192);
        gload_lds16(pb0, lB + boff);
    };
    auto STAGE_B3 = [&](int aoff, int boff) {
        gload_lds16(pa2, lA + aoff + 16384);
        gload_lds16(pa3, lA + aoff + 24576);
        gload_lds16(pb1, lB + boff + 8192);
        pa0 += 128; pa1 += 128; pa2 += 128; pa3 += 128;
        pb0 += 128; pb1 += 128;
    };

    const int arow_b = (wr * 64 + lr) * 128;
    const int brow_b = (wc * 64 + lr) * 128;
    const int x0 = ((lh)     ^ (lr & 7)) * 16;
    const int x1 = ((4 + lh) ^ (lr & 7)) * 16;

    f32x4 acc[4][4] = {};

    STAGE_A3(0, 0);           STAGE_B3(0, 0);
    STAGE_A3(32768, 16384);   STAGE_B3(32768, 16384);

    int cA = 0, cB = 0;
    int sA = 65536, sB = 32768;

    for (int t = 0; t < NT; ++t) {
        if (t < NT - 1) asm volatile("s_waitcnt vmcnt(6)" ::: "memory");
        else            asm volatile("s_waitcnt vmcnt(0)" ::: "memory");
        __builtin_amdgcn_s_barrier();
        __builtin_amdgcn_sched_barrier(0);

        const char* ab = AL + cA;
        const char* bb = BL + cB;
        const bool st = (t < NT - 2);

        short8 bfr[4][2], afr[2][2];
        #pragma unroll
        for (int ni = 0; ni < 4; ++ni) {
            bfr[ni][0] = *(const short8*)(bb + brow_b + ni * 2048 + x0);
            bfr[ni][1] = *(const short8*)(bb + brow_b + ni * 2048 + x1);
        }
        #pragma unroll
        for (int mi = 0; mi < 2; ++mi) {
            afr[mi][0] = *(const short8*)(ab + arow_b + mi * 2048 + x0);
            afr[mi][1] = *(const short8*)(ab + arow_b + mi * 2048 + x1);
        }
        if (st) STAGE_A3(sA, sB);
        __builtin_amdgcn_s_barrier();
        asm volatile("s_waitcnt lgkmcnt(0)" ::: "memory");
        __builtin_amdgcn_sched_barrier(0);
        __builtin_amdgcn_s_setprio(1);
        #pragma unroll
        for (int mi = 0; mi < 2; ++mi)
            #pragma unroll
            for (int ni = 0; ni < 4; ++ni)
                #pragma unroll
                for (int ks = 0; ks < 2; ++ks)
                    acc[mi][ni] = __builtin_amdgcn_mfma_f32_16x16x32_bf16(
                        afr[mi][ks], bfr[ni][ks], acc[mi][ni], 0, 0, 0);
        __builtin_amdgcn_s_setprio(0);
        __builtin_amdgcn_s_barrier();

        short8 afr2[2][2];
        #pragma unroll
        for (int mi = 0; mi < 2; ++mi) {
            afr2[mi][0] = *(const short8*)(ab + arow_b + (mi + 2) * 2048 + x0);
            afr2[mi][1] = *(const short8*)(ab + arow_b + (mi + 2) * 2048 + x1);
        }
        if (st) STAGE_B3(sA, sB);
        __builtin_amdgcn_s_barrier();
        asm volatile("s_waitcnt lgkmcnt(0)" ::: "memory");
        __builtin_amdgcn_sched_barrier(0);
        __builtin_amdgcn_s_setprio(1);
        #pragma unroll
        for (int mi = 0; mi < 2; ++mi)
            #pragma unroll
            for (int ni = 0; ni < 4; ++ni)
                #pragma unroll
                for (int ks = 0; ks < 2; ++ks)
                    acc[mi + 2][ni] = __builtin_amdgcn_mfma_f32_16x16x32_bf16(
                        afr2[mi][ks], bfr[ni][ks], acc[mi + 2][ni], 0, 0, 0);
        __builtin_amdgcn_s_setprio(0);

        cA = (cA == 65536) ? 0 : cA + 32768;
        cB = (cB == 32768) ? 0 : cB + 16384;
        sA = (sA == 65536) ? 0 : sA + 32768;
        sB = (sB == 32768) ? 0 : sB + 16384;
    }

    if constexpr (MODE == 1) {
        const long nbase = n0 + wc * 64;      // wave-uniform, 64-aligned
        const int kk = (int)(nbase >> 10);    // 0=q 1=k 2=v (uniform)
        const int h = (int)((nbase & 1023) >> 6);
        if (kk == 2) {
            float lam = lambp[0];
            #pragma unroll
            for (int i = 0; i < 4; ++i)
            #pragma unroll
            for (int j = 0; j < 4; ++j) {
                unsigned short pk[4];
                #pragma unroll
                for (int r = 0; r < 4; ++r) {
                    long m = m0 + wr * 64 + i * 16 + lh * 4 + r;
                    int d = j * 16 + lr;
                    int rem = h * 64 + d;
                    long b_ = m >> 11, t = m & 2047;
                    size_t idx = (((size_t)(b_ * 16 + h)) * 2048 + t) * 64 + d;
                    float vv = v1[(size_t)m * 1024 + rem];
                    float val = (1.0f - lam) * acc[i][j][r] + lam * vv;
                    vout[idx] = val;
                    pk[r] = f2bf(val);
                }
                // 4 consecutive-t bf16 -> one 8-B store (tb multiple of 4;
                // all 4 rows share b_ since blocks never straddle b*2048)
                long mb = m0 + wr * 64 + i * 16 + lh * 4;
                long b_ = mb >> 11;
                int tb = (int)(mb & 2047);
                int d = j * 16 + lr;
                *(ushort4*)&vbT[(((size_t)(b_ * 16 + h)) * 64 + d) * 2048 + tb] =
                    *(ushort4*)pk;
            }
        } else {
            unsigned short* dst = (kk == 0) ? qbuf : kbuf;
            #pragma unroll
            for (int i = 0; i < 4; ++i)
            #pragma unroll
            for (int r = 0; r < 4; ++r) {
                float v0 = acc[i][0][r], v1_ = acc[i][1][r];
                float v2 = acc[i][2][r], v3 = acc[i][3][r];
                float ss = v0 * v0 + v1_ * v1_ + v2 * v2 + v3 * v3;
                ss += __shfl_xor(ss, 1);
                ss += __shfl_xor(ss, 2);
                ss += __shfl_xor(ss, 4);
                ss += __shfl_xor(ss, 8);
                float inv = rsqrtf(ss * (1.0f / 64.0f) + 1e-6f);
                float x0f = v0 * inv, x1f = v1_ * inv;
                float x2f = v2 * inv, x3f = v3 * inv;
                long m = m0 + wr * 64 + i * 16 + lh * 4 + r;
                int t = (int)(m & 2047);
                long b_ = m >> 11;
                float c0 = cosT[t * 32 + lr],      s0 = sinT[t * 32 + lr];
                float c1 = cosT[t * 32 + 16 + lr], s1 = sinT[t * 32 + 16 + lr];
                size_t rb = (((size_t)(b_ * 16 + h)) * 2048 + t) * 64;
                dst[rb + 0 * 16 + lr] = f2bf( x0f * c0 + x2f * s0);
                dst[rb + 1 * 16 + lr] = f2bf( x1f * c1 + x3f * s1);
                dst[rb + 2 * 16 + lr] = f2bf(-x0f * s0 + x2f * c0);
                dst[rb + 3 * 16 + lr] = f2bf(-x1f * s1 + x3f * c1);
            }
        }
    } else {
        #pragma unroll
        for (int i = 0; i < 4; ++i)
        #pragma unroll
        for (int j = 0; j < 4; ++j)
        #pragma unroll
        for (int r = 0; r < 4; ++r) {
            long m = m0 + wr * 64 + i * 16 + lh * 4 + r;
            long n = n0 + wc * 64 + j * 16 + lr;
            y[(size_t)m * 1024 + n] = acc[i][j][r] + bias[n];
        }
    }
}

// ---------------- flash attention, sliding window (round-4 proven) -------
__global__ __launch_bounds__(512, 2) void attn_kernel(
    const unsigned short* __restrict__ qn, const unsigned short* __restrict__ kn,
    const unsigned short* __restrict__ vtb, unsigned short* __restrict__ attn_out,
    const int* __restrict__ winp)
{
    __shared__ unsigned short Ks[2][64 * 64];    // [key][d], swizzled
    __shared__ unsigned short Vt[2][64 * 64];    // [d][key], swizzled
    __shared__ unsigned short Pl[8][16 * 72];    // per-wave P: [qrow][key]
    const int tid = threadIdx.x, lane = tid & 63, w = tid >> 6;
    const int lr = lane & 15, lh = lane >> 4;
    const int bh = blockIdx.x;                   // 0..63
    const int qt2 = blockIdx.y;                  // 0..15
    const int t0 = qt2 * 128;
    const int win = winp[0];
    const int qrow = t0 + w * 16;

    short8 qf[2];
    #pragma unroll
    for (int ks = 0; ks < 2; ++ks)
        qf[ks] = *(const short8*)&qn[((size_t)bh * 2048 + qrow + lr) * 64 + ks * 32 + lh * 8];

    const int srow = tid >> 3;
    const int scol = (tid & 7) ^ (srow & 7);
    const char* kg = (const char*)kn + ((size_t)bh * 2048 + srow) * 128 + scol * 16;
    const char* vg = (const char*)vtb + ((size_t)(bh * 64 + srow)) * 4096 + scol * 16;
    char* lk = (char*)&Ks[0][0] + w * 1024;
    char* lv = (char*)&Vt[0][0] + w * 1024;

    auto STAGE = [&](int buf, int j0) {
        gload_lds16(kg + (size_t)j0 * 128, lk + buf * 8192);
        gload_lds16(vg + (size_t)j0 * 2,   lv + buf * 8192);
    };

    f32x4 oacc[4] = {};
    float mrow[4], lrow[4];
    #pragma unroll
    for (int r = 0; r < 4; ++r) { mrow[r] = -1e30f; lrow[r] = 0.f; }

    const float C = 0.125f * 1.44269504f;   // scale * log2(e)
    const int kvt0 = max(0, t0 - win + 1) >> 6;
    const int kvt1 = (t0 + 127) >> 6;

    STAGE(0, kvt0 * 64);
    __syncthreads();
    for (int kvt = kvt0; kvt <= kvt1; ++kvt) {
        const int j0 = kvt * 64;
        const int buf = (kvt - kvt0) & 1;
        if (kvt < kvt1) STAGE(buf ^ 1, j0 + 64);

        if (j0 <= qrow + 15 && j0 + 63 >= qrow + 16 - win) {
            const char* ksb = (const char*)&Ks[buf][0];
            const char* vtb_ = (const char*)&Vt[buf][0];

            float sv[4][4];
            #pragma unroll
            for (int kt = 0; kt < 4; ++kt) {
                f32x4 s = {};
                #pragma unroll
                for (int ks = 0; ks < 2; ++ks) {
                    int row = kt * 16 + lr;
                    int off = row * 128 + (((ks * 4 + lh) ^ (row & 7)) * 16);
                    short8 kf = *(const short8*)(ksb + off);
                    s = __builtin_amdgcn_mfma_f32_16x16x32_bf16(qf[ks], kf, s, 0, 0, 0);
                }
                #pragma unroll
                for (int r = 0; r < 4; ++r) {
                    int qi = qrow + lh * 4 + r;
                    int ji = j0 + kt * 16 + lr;
                    bool ok = (ji <= qi) && (qi - ji < win);
                    sv[kt][r] = ok ? s[r] * C : -1e30f;
                }
            }

            float pn[4][4];
            #pragma unroll
            for (int r = 0; r < 4; ++r) {
                float tm = fmaxf(fmaxf(sv[0][r], sv[1][r]), fmaxf(sv[2][r], sv[3][r]));
                #pragma unroll
                for (int m = 1; m < 16; m <<= 1) tm = fmaxf(tm, __shfl_xor(tm, m));
                float nm = fmaxf(mrow[r], tm);
                float alpha = exp2f(mrow[r] - nm);
                float ps = 0.f;
                #pragma unroll
                for (int kt = 0; kt < 4; ++kt) {
                    float p = exp2f(sv[kt][r] - nm);
                    pn[kt][r] = p; ps += p;
                }
                #pragma unroll
                for (int m = 1; m < 16; m <<= 1) ps += __shfl_xor(ps, m);
                lrow[r] = lrow[r] * alpha + ps;
                mrow[r] = nm;
                #pragma unroll
                for (int dt = 0; dt < 4; ++dt) oacc[dt][r] *= alpha;
            }

            #pragma unroll
            for (int kt = 0; kt < 4; ++kt)
                #pragma unroll
                for (int r = 0; r < 4; ++r)
                    Pl[w][(lh * 4 + r) * 72 + kt * 16 + lr] = f2bf(pn[kt][r]);

            short8 pf[2];
            #pragma unroll
            for (int ks = 0; ks < 2; ++ks)
                pf[ks] = *(const short8*)&Pl[w][lr * 72 + ks * 32 + lh * 8];
            #pragma unroll
            for (int dt = 0; dt < 4; ++dt)
                #pragma unroll
                for (int ks = 0; ks < 2; ++ks) {
                    int row = dt * 16 + lr;
                    int off = row * 128 + (((ks * 4 + lh) ^ (row & 7)) * 16);
                    short8 vf = *(const short8*)(vtb_ + off);
                    oacc[dt] = __builtin_amdgcn_mfma_f32_16x16x32_bf16(pf[ks], vf, oacc[dt], 0, 0, 0);
                }
        }
        __syncthreads();
    }

    int b = bh >> 4, h = bh & 15;
    #pragma unroll
    for (int dt = 0; dt < 4; ++dt)
        #pragma unroll
        for (int r = 0; r < 4; ++r) {
            int t = qrow + lh * 4 + r;
            float o = oacc[dt][r] / lrow[r];
            attn_out[((size_t)b * 2048 + t) * 1024 + h * 64 + dt * 16 + lr] = f2bf(o);
        }
}

extern "C" void kernel_launch(void* const* d_in, const int* in_sizes, int n_in,
                              void* d_out, int out_size, void* d_ws, size_t ws_size,
                              hipStream_t stream) {
    const float* x    = (const float*)d_in[0];
    const float* v1   = (const float*)d_in[1];
    const float* qkvw = (const float*)d_in[2];
    const float* cpw  = (const float*)d_in[3];
    const float* cpb  = (const float*)d_in[4];
    const float* lamb = (const float*)d_in[5];
    const int*   winp = (const int*)d_in[6];

    float* y    = (float*)d_out;
    float* vout = y + (size_t)8192 * 1024;   // value output (B,H,T,64) fp32

    // V^T bf16 scratch lives in the y region of d_out; proj overwrites y after.
    unsigned short* vbT = (unsigned short*)y;

    char* ws = (char*)d_ws;
    unsigned short* xb   = (unsigned short*)(ws);                 // 16MB (reused as attn_out)
    unsigned short* Wb   = (unsigned short*)(ws + (16u << 20));   // 6MB
    unsigned short* Wp   = (unsigned short*)(ws + (22u << 20));   // 2MB
    unsigned short* qbuf = (unsigned short*)(ws + (24u << 20));   // 16MB
    unsigned short* kbuf = (unsigned short*)(ws + (40u << 20));   // 16MB
    float* cosT = (float*)(ws + (56u << 20));                     // 256KB
    float* sinT = (float*)(ws + (56u << 20) + (256u << 10));      // 256KB

    cvt3_kernel<<<12288, 256, 0, stream>>>(x, qkvw, cpw, xb, Wb, Wp);
    rope_tables<<<65536 / 256, 256, 0, stream>>>(cosT, sinT);

    gemm8p<1><<<768, 512, 0, stream>>>(xb, Wb, 1024,
        qbuf, kbuf, vout, vbT, v1, lamb, nullptr, nullptr, cosT, sinT);

    attn_kernel<<<dim3(64, 16), 512, 0, stream>>>(qbuf, kbuf, vbT, xb, winp);

    gemm8p<2><<<256, 512, 0, stream>>>(xb, Wp, 1024,
        nullptr, nullptr, nullptr, nullptr, nullptr, nullptr, y, cpb, nullptr, nullptr);
}

// Round 16
// 179.653 us; speedup vs baseline: 1.0518x; 1.0518x over previous
//
#include <hip/hip_runtime.h>
#include <stdint.h>

typedef __attribute__((ext_vector_type(8))) short short8;   // 8 bf16 (4 VGPRs)
typedef __attribute__((ext_vector_type(4))) float f32x4;

#define LDS_AS __attribute__((address_space(3)))
#define GLOB_AS __attribute__((address_space(1)))

__device__ __forceinline__ void gload_lds16(const void* g, void* l) {
    __builtin_amdgcn_global_load_lds((const GLOB_AS uint32_t*)g,
                                     (LDS_AS uint32_t*)l, 16, 0, 0);
}

__device__ __forceinline__ unsigned short f2bf(float f) {
    uint32_t u = __builtin_bit_cast(uint32_t, f);
    u += 0x7fffu + ((u >> 16) & 1u);
    return (unsigned short)(u >> 16);
}
__device__ __forceinline__ float bf2f(unsigned short u) {
    uint32_t v = ((uint32_t)u) << 16;
    return __builtin_bit_cast(float, v);
}

// ------------- fused fp32 -> bf16 convert (x, qkv_w, proj_w) -------------
__global__ void cvt3_kernel(const float* __restrict__ s0,
                            const float* __restrict__ s1,
                            const float* __restrict__ s2,
                            unsigned short* __restrict__ d0,
                            unsigned short* __restrict__ d1,
                            unsigned short* __restrict__ d2) {
    long e = ((long)blockIdx.x * blockDim.x + threadIdx.x) * 4;
    const float* s; unsigned short* d; long off;
    if (e < 8388608)        { s = s0; d = d0; off = e; }
    else if (e < 11534336)  { s = s1; d = d1; off = e - 8388608; }
    else                    { s = s2; d = d2; off = e - 11534336; }
    float4 v = *(const float4*)(s + off);
    ushort4 o;
    o.x = f2bf(v.x); o.y = f2bf(v.y); o.z = f2bf(v.z); o.w = f2bf(v.w);
    *(ushort4*)(d + off) = o;
}

// ---------------- rope tables: cos/sin (2048 x 32) ----------------
__global__ void rope_tables(float* __restrict__ cosT, float* __restrict__ sinT) {
    int tid = blockIdx.x * blockDim.x + threadIdx.x;  // 65536
    int t = tid >> 5, i = tid & 31;
    float f = (i < 16) ? exp2f(-10.0f * (float)i / 15.0f) : 0.0f;
    float th = (float)t * f;
    cosT[tid] = cosf(th);
    sinT[tid] = sinf(th);
}

// ==== GEMM (round-8 champion + packed vbT stores, register-built) ========
// BM=256 BN=128, 8 waves (4M x 2N, 64x64/wave), 3-K-tile LDS ring,
// counted vmcnt(6), XCD-L2 tile mapping. vbT epilogue: 4 consecutive-t bf16
// packed into one ushort4 (8-B) store, built in registers (no local array).
// MODE 1: qkv epilogue (q/k RMS+RoPE; v lerp -> vout + vbT). MODE 2: +bias.
template <int MODE>
__global__ __launch_bounds__(512, 2) void gemm8p(
    const unsigned short* __restrict__ A, const unsigned short* __restrict__ B,
    int K,
    unsigned short* __restrict__ qbuf, unsigned short* __restrict__ kbuf,
    float* __restrict__ vout, unsigned short* __restrict__ vbT,
    const float* __restrict__ v1, const float* __restrict__ lambp,
    float* __restrict__ y, const float* __restrict__ bias,
    const float* __restrict__ cosT, const float* __restrict__ sinT)
{
    __shared__ __align__(16) char smem[147456];   // A ring 98304 + B ring 49152
    char* const AL = smem;
    char* const BL = smem + 98304;
    const int tid = threadIdx.x, lane = tid & 63, w = tid >> 6;
    const int wr = w >> 1, wc = w & 1;
    const int lr = lane & 15, lh = lane >> 4;

    // XCD-L2 tile mapping (XCD = id%8 round-robin assumption)
    const int id = blockIdx.x;
    const long m0 = (long)((id & 7) * 4 + ((id >> 3) & 3)) * 256;
    const long n0 = (long)(id >> 5) * 128;
    const int NT = K >> 6;

    const int srow = tid >> 3;
    const int swc  = (tid & 7) ^ (srow & 7);
    const long rsb = (long)K * 2;
    const char* pa0 = (const char*)A + (m0 + srow +   0) * rsb + swc * 16;
    const char* pa1 = (const char*)A + (m0 + srow +  64) * rsb + swc * 16;
    const char* pa2 = (const char*)A + (m0 + srow + 128) * rsb + swc * 16;
    const char* pa3 = (const char*)A + (m0 + srow + 192) * rsb + swc * 16;
    const char* pb0 = (const char*)B + (n0 + srow +   0) * rsb + swc * 16;
    const char* pb1 = (const char*)B + (n0 + srow +  64) * rsb + swc * 16;
    char* const lA = AL + w * 1024;
    char* const lB = BL + w * 1024;

    auto STAGE_A3 = [&](int aoff, int boff) {
        gload_lds16(pa0, lA + aoff);
        gload_lds16(pa1, lA + aoff + 8192);
        gload_lds16(pb0, lB + boff);
    };
    auto STAGE_B3 = [&](int aoff, int boff) {
        gload_lds16(pa2, lA + aoff + 16384);
        gload_lds16(pa3, lA + aoff + 24576);
        gload_lds16(pb1, lB + boff + 8192);
        pa0 += 128; pa1 += 128; pa2 += 128; pa3 += 128;
        pb0 += 128; pb1 += 128;
    };

    const int arow_b = (wr * 64 + lr) * 128;
    const int brow_b = (wc * 64 + lr) * 128;
    const int x0 = ((lh)     ^ (lr & 7)) * 16;
    const int x1 = ((4 + lh) ^ (lr & 7)) * 16;

    f32x4 acc[4][4] = {};

    STAGE_A3(0, 0);           STAGE_B3(0, 0);
    STAGE_A3(32768, 16384);   STAGE_B3(32768, 16384);

    int cA = 0, cB = 0;
    int sA = 65536, sB = 32768;

    for (int t = 0; t < NT; ++t) {
        if (t < NT - 1) asm volatile("s_waitcnt vmcnt(6)" ::: "memory");
        else            asm volatile("s_waitcnt vmcnt(0)" ::: "memory");
        __builtin_amdgcn_s_barrier();
        __builtin_amdgcn_sched_barrier(0);

        const char* ab = AL + cA;
        const char* bb = BL + cB;
        const bool st = (t < NT - 2);

        short8 bfr[4][2], afr[2][2];
        #pragma unroll
        for (int ni = 0; ni < 4; ++ni) {
            bfr[ni][0] = *(const short8*)(bb + brow_b + ni * 2048 + x0);
            bfr[ni][1] = *(const short8*)(bb + brow_b + ni * 2048 + x1);
        }
        #pragma unroll
        for (int mi = 0; mi < 2; ++mi) {
            afr[mi][0] = *(const short8*)(ab + arow_b + mi * 2048 + x0);
            afr[mi][1] = *(const short8*)(ab + arow_b + mi * 2048 + x1);
        }
        if (st) STAGE_A3(sA, sB);
        __builtin_amdgcn_s_barrier();
        asm volatile("s_waitcnt lgkmcnt(0)" ::: "memory");
        __builtin_amdgcn_sched_barrier(0);
        __builtin_amdgcn_s_setprio(1);
        #pragma unroll
        for (int mi = 0; mi < 2; ++mi)
            #pragma unroll
            for (int ni = 0; ni < 4; ++ni)
                #pragma unroll
                for (int ks = 0; ks < 2; ++ks)
                    acc[mi][ni] = __builtin_amdgcn_mfma_f32_16x16x32_bf16(
                        afr[mi][ks], bfr[ni][ks], acc[mi][ni], 0, 0, 0);
        __builtin_amdgcn_s_setprio(0);
        __builtin_amdgcn_s_barrier();

        short8 afr2[2][2];
        #pragma unroll
        for (int mi = 0; mi < 2; ++mi) {
            afr2[mi][0] = *(const short8*)(ab + arow_b + (mi + 2) * 2048 + x0);
            afr2[mi][1] = *(const short8*)(ab + arow_b + (mi + 2) * 2048 + x1);
        }
        if (st) STAGE_B3(sA, sB);
        __builtin_amdgcn_s_barrier();
        asm volatile("s_waitcnt lgkmcnt(0)" ::: "memory");
        __builtin_amdgcn_sched_barrier(0);
        __builtin_amdgcn_s_setprio(1);
        #pragma unroll
        for (int mi = 0; mi < 2; ++mi)
            #pragma unroll
            for (int ni = 0; ni < 4; ++ni)
                #pragma unroll
                for (int ks = 0; ks < 2; ++ks)
                    acc[mi + 2][ni] = __builtin_amdgcn_mfma_f32_16x16x32_bf16(
                        afr2[mi][ks], bfr[ni][ks], acc[mi + 2][ni], 0, 0, 0);
        __builtin_amdgcn_s_setprio(0);

        cA = (cA == 65536) ? 0 : cA + 32768;
        cB = (cB == 32768) ? 0 : cB + 16384;
        sA = (sA == 65536) ? 0 : sA + 32768;
        sB = (sB == 32768) ? 0 : sB + 16384;
    }

    if constexpr (MODE == 1) {
        const long nbase = n0 + wc * 64;      // wave-uniform, 64-aligned
        const int kk = (int)(nbase >> 10);    // 0=q 1=k 2=v (uniform)
        const int h = (int)((nbase & 1023) >> 6);
        if (kk == 2) {
            float lam = lambp[0];
            #pragma unroll
            for (int i = 0; i < 4; ++i)
            #pragma unroll
            for (int j = 0; j < 4; ++j) {
                const long mb = m0 + wr * 64 + i * 16 + lh * 4;
                const long b_ = mb >> 11;
                const int tb = (int)(mb & 2047);
                const int d = j * 16 + lr;
                const int rem = h * 64 + d;
                float va[4];
                #pragma unroll
                for (int r = 0; r < 4; ++r) {
                    float vv = v1[(size_t)(mb + r) * 1024 + rem];
                    va[r] = (1.0f - lam) * acc[i][j][r] + lam * vv;
                    vout[(((size_t)(b_ * 16 + h)) * 2048 + tb + r) * 64 + d] = va[r];
                }
                // 4 consecutive-t bf16 -> one 8-B store, built in registers
                ushort4 o;
                o.x = f2bf(va[0]); o.y = f2bf(va[1]);
                o.z = f2bf(va[2]); o.w = f2bf(va[3]);
                *(ushort4*)&vbT[(((size_t)(b_ * 16 + h)) * 64 + d) * 2048 + tb] = o;
            }
        } else {
            unsigned short* dst = (kk == 0) ? qbuf : kbuf;
            #pragma unroll
            for (int i = 0; i < 4; ++i)
            #pragma unroll
            for (int r = 0; r < 4; ++r) {
                float v0 = acc[i][0][r], v1_ = acc[i][1][r];
                float v2 = acc[i][2][r], v3 = acc[i][3][r];
                float ss = v0 * v0 + v1_ * v1_ + v2 * v2 + v3 * v3;
                ss += __shfl_xor(ss, 1);
                ss += __shfl_xor(ss, 2);
                ss += __shfl_xor(ss, 4);
                ss += __shfl_xor(ss, 8);
                float inv = rsqrtf(ss * (1.0f / 64.0f) + 1e-6f);
                float x0f = v0 * inv, x1f = v1_ * inv;
                float x2f = v2 * inv, x3f = v3 * inv;
                long m = m0 + wr * 64 + i * 16 + lh * 4 + r;
                int t = (int)(m & 2047);
                long b_ = m >> 11;
                float c0 = cosT[t * 32 + lr],      s0 = sinT[t * 32 + lr];
                float c1 = cosT[t * 32 + 16 + lr], s1 = sinT[t * 32 + 16 + lr];
                size_t rb = (((size_t)(b_ * 16 + h)) * 2048 + t) * 64;
                dst[rb + 0 * 16 + lr] = f2bf( x0f * c0 + x2f * s0);
                dst[rb + 1 * 16 + lr] = f2bf( x1f * c1 + x3f * s1);
                dst[rb + 2 * 16 + lr] = f2bf(-x0f * s0 + x2f * c0);
                dst[rb + 3 * 16 + lr] = f2bf(-x1f * s1 + x3f * c1);
            }
        }
    } else {
        #pragma unroll
        for (int i = 0; i < 4; ++i)
        #pragma unroll
        for (int j = 0; j < 4; ++j)
        #pragma unroll
        for (int r = 0; r < 4; ++r) {
            long m = m0 + wr * 64 + i * 16 + lh * 4 + r;
            long n = n0 + wc * 64 + j * 16 + lr;
            y[(size_t)m * 1024 + n] = acc[i][j][r] + bias[n];
        }
    }
}

// ---------------- flash attention, sliding window (round-4 proven) -------
__global__ __launch_bounds__(512, 2) void attn_kernel(
    const unsigned short* __restrict__ qn, const unsigned short* __restrict__ kn,
    const unsigned short* __restrict__ vtb, unsigned short* __restrict__ attn_out,
    const int* __restrict__ winp)
{
    __shared__ unsigned short Ks[2][64 * 64];    // [key][d], swizzled
    __shared__ unsigned short Vt[2][64 * 64];    // [d][key], swizzled
    __shared__ unsigned short Pl[8][16 * 72];    // per-wave P: [qrow][key]
    const int tid = threadIdx.x, lane = tid & 63, w = tid >> 6;
    const int lr = lane & 15, lh = lane >> 4;
    const int bh = blockIdx.x;                   // 0..63
    const int qt2 = blockIdx.y;                  // 0..15
    const int t0 = qt2 * 128;
    const int win = winp[0];
    const int qrow = t0 + w * 16;

    short8 qf[2];
    #pragma unroll
    for (int ks = 0; ks < 2; ++ks)
        qf[ks] = *(const short8*)&qn[((size_t)bh * 2048 + qrow + lr) * 64 + ks * 32 + lh * 8];

    const int srow = tid >> 3;
    const int scol = (tid & 7) ^ (srow & 7);
    const char* kg = (const char*)kn + ((size_t)bh * 2048 + srow) * 128 + scol * 16;
    const char* vg = (const char*)vtb + ((size_t)(bh * 64 + srow)) * 4096 + scol * 16;
    char* lk = (char*)&Ks[0][0] + w * 1024;
    char* lv = (char*)&Vt[0][0] + w * 1024;

    auto STAGE = [&](int buf, int j0) {
        gload_lds16(kg + (size_t)j0 * 128, lk + buf * 8192);
        gload_lds16(vg + (size_t)j0 * 2,   lv + buf * 8192);
    };

    f32x4 oacc[4] = {};
    float mrow[4], lrow[4];
    #pragma unroll
    for (int r = 0; r < 4; ++r) { mrow[r] = -1e30f; lrow[r] = 0.f; }

    const float C = 0.125f * 1.44269504f;   // scale * log2(e)
    const int kvt0 = max(0, t0 - win + 1) >> 6;
    const int kvt1 = (t0 + 127) >> 6;

    STAGE(0, kvt0 * 64);
    __syncthreads();
    for (int kvt = kvt0; kvt <= kvt1; ++kvt) {
        const int j0 = kvt * 64;
        const int buf = (kvt - kvt0) & 1;
        if (kvt < kvt1) STAGE(buf ^ 1, j0 + 64);

        if (j0 <= qrow + 15 && j0 + 63 >= qrow + 16 - win) {
            const char* ksb = (const char*)&Ks[buf][0];
            const char* vtb_ = (const char*)&Vt[buf][0];

            float sv[4][4];
            #pragma unroll
            for (int kt = 0; kt < 4; ++kt) {
                f32x4 s = {};
                #pragma unroll
                for (int ks = 0; ks < 2; ++ks) {
                    int row = kt * 16 + lr;
                    int off = row * 128 + (((ks * 4 + lh) ^ (row & 7)) * 16);
                    short8 kf = *(const short8*)(ksb + off);
                    s = __builtin_amdgcn_mfma_f32_16x16x32_bf16(qf[ks], kf, s, 0, 0, 0);
                }
                #pragma unroll
                for (int r = 0; r < 4; ++r) {
                    int qi = qrow + lh * 4 + r;
                    int ji = j0 + kt * 16 + lr;
                    bool ok = (ji <= qi) && (qi - ji < win);
                    sv[kt][r] = ok ? s[r] * C : -1e30f;
                }
            }

            float pn[4][4];
            #pragma unroll
            for (int r = 0; r < 4; ++r) {
                float tm = fmaxf(fmaxf(sv[0][r], sv[1][r]), fmaxf(sv[2][r], sv[3][r]));
                #pragma unroll
                for (int m = 1; m < 16; m <<= 1) tm = fmaxf(tm, __shfl_xor(tm, m));
                float nm = fmaxf(mrow[r], tm);
                float alpha = exp2f(mrow[r] - nm);
                float ps = 0.f;
                #pragma unroll
                for (int kt = 0; kt < 4; ++kt) {
                    float p = exp2f(sv[kt][r] - nm);
                    pn[kt][r] = p; ps += p;
                }
                #pragma unroll
                for (int m = 1; m < 16; m <<= 1) ps += __shfl_xor(ps, m);
                lrow[r] = lrow[r] * alpha + ps;
                mrow[r] = nm;
                #pragma unroll
                for (int dt = 0; dt < 4; ++dt) oacc[dt][r] *= alpha;
            }

            #pragma unroll
            for (int kt = 0; kt < 4; ++kt)
                #pragma unroll
                for (int r = 0; r < 4; ++r)
                    Pl[w][(lh * 4 + r) * 72 + kt * 16 + lr] = f2bf(pn[kt][r]);

            short8 pf[2];
            #pragma unroll
            for (int ks = 0; ks < 2; ++ks)
                pf[ks] = *(const short8*)&Pl[w][lr * 72 + ks * 32 + lh * 8];
            #pragma unroll
            for (int dt = 0; dt < 4; ++dt)
                #pragma unroll
                for (int ks = 0; ks < 2; ++ks) {
                    int row = dt * 16 + lr;
                    int off = row * 128 + (((ks * 4 + lh) ^ (row & 7)) * 16);
                    short8 vf = *(const short8*)(vtb_ + off);
                    oacc[dt] = __builtin_amdgcn_mfma_f32_16x16x32_bf16(pf[ks], vf, oacc[dt], 0, 0, 0);
                }
        }
        __syncthreads();
    }

    int b = bh >> 4, h = bh & 15;
    #pragma unroll
    for (int dt = 0; dt < 4; ++dt)
        #pragma unroll
        for (int r = 0; r < 4; ++r) {
            int t = qrow + lh * 4 + r;
            float o = oacc[dt][r] / lrow[r];
            attn_out[((size_t)b * 2048 + t) * 1024 + h * 64 + dt * 16 + lr] = f2bf(o);
        }
}

extern "C" void kernel_launch(void* const* d_in, const int* in_sizes, int n_in,
                              void* d_out, int out_size, void* d_ws, size_t ws_size,
                              hipStream_t stream) {
    const float* x    = (const float*)d_in[0];
    const float* v1   = (const float*)d_in[1];
    const float* qkvw = (const float*)d_in[2];
    const float* cpw  = (const float*)d_in[3];
    const float* cpb  = (const float*)d_in[4];
    const float* lamb = (const float*)d_in[5];
    const int*   winp = (const int*)d_in[6];

    float* y    = (float*)d_out;
    float* vout = y + (size_t)8192 * 1024;   // value output (B,H,T,64) fp32

    // V^T bf16 scratch lives in the y region of d_out; proj overwrites y after.
    unsigned short* vbT = (unsigned short*)y;

    char* ws = (char*)d_ws;
    unsigned short* xb   = (unsigned short*)(ws);                 // 16MB (reused as attn_out)
    unsigned short* Wb   = (unsigned short*)(ws + (16u << 20));   // 6MB
    unsigned short* Wp   = (unsigned short*)(ws + (22u << 20));   // 2MB
    unsigned short* qbuf = (unsigned short*)(ws + (24u << 20));   // 16MB
    unsigned short* kbuf = (unsigned short*)(ws + (40u << 20));   // 16MB
    float* cosT = (float*)(ws + (56u << 20));                     // 256KB
    float* sinT = (float*)(ws + (56u << 20) + (256u << 10));      // 256KB

    cvt3_kernel<<<12288, 256, 0, stream>>>(x, qkvw, cpw, xb, Wb, Wp);
    rope_tables<<<65536 / 256, 256, 0, stream>>>(cosT, sinT);

    gemm8p<1><<<768, 512, 0, stream>>>(xb, Wb, 1024,
        qbuf, kbuf, vout, vbT, v1, lamb, nullptr, nullptr, cosT, sinT);

    attn_kernel<<<dim3(64, 16), 512, 0, stream>>>(qbuf, kbuf, vbT, xb, winp);

    gemm8p<2><<<256, 512, 0, stream>>>(xb, Wp, 1024,
        nullptr, nullptr, nullptr, nullptr, nullptr, nullptr, y, cpb, nullptr, nullptr);
}